// Round 1
// baseline (84079.810 us; speedup 1.0000x reference)
//
#include <hip/hip_runtime.h>

#define SQ 1800
#define NB 4

__device__ __forceinline__ float bf2f(unsigned short u){ return __uint_as_float(((unsigned)u)<<16); }
__device__ __forceinline__ unsigned short f2bf(float f){
  unsigned u=__float_as_uint(f);
  unsigned r=u+0x7FFFu+((u>>16)&1u);
  return (unsigned short)(r>>16);
}
__device__ __forceinline__ float sigm(float x){ return 1.0f/(1.0f+__expf(-x)); }

// ---------------- prep kernels ----------------

// sinusoid table rows 1..S (row index t -> table position t+1), [1800][200] f32
__global__ __launch_bounds__(256) void k_postab(float* __restrict__ pt){
  int idx=blockIdx.x*256+threadIdx.x; if(idx>=SQ*200) return;
  int t=idx/200, j=idx%200;
  double ang=(double)(t+1)*pow(10000.0, -(double)(2*(j/2))/200.0);
  pt[idx]=(float)((j&1)? cos(ang) : sin(ang));
}

// W_e[k][j] = sum_m tgt_W[k][m] * Wih1[m][j]   (72 x 4096)
__global__ __launch_bounds__(256) void k_we(const float* __restrict__ tgtW, const float* __restrict__ Wih1, float* __restrict__ We){
  int idx=blockIdx.x*256+threadIdx.x; // exactly 72*4096
  int k=idx>>12, j=idx&4095;
  float acc=0.f;
  for(int m=0;m<200;m++) acc+=tgtW[k*200+m]*Wih1[(size_t)m*4096+j];
  We[idx]=acc;
}

// bias[3][4096]: cell0 = tgt_b@Wih1 + bih1 + bhh1 ; cell1 = bih2+bhh2 ; cell2 = bih3+bhh3
__global__ __launch_bounds__(256) void k_bias(const float* __restrict__ tgtb, const float* __restrict__ Wih1,
    const float* __restrict__ bih1,const float* __restrict__ bhh1,const float* __restrict__ bih2,const float* __restrict__ bhh2,
    const float* __restrict__ bih3,const float* __restrict__ bhh3,float* __restrict__ bias){
  int idx=blockIdx.x*256+threadIdx.x; if(idx>=3*4096) return;
  int l=idx>>12, j=idx&4095;
  float v;
  if(l==0){ v=bih1[j]+bhh1[j]; for(int m=0;m<200;m++) v+=tgtb[m]*Wih1[(size_t)m*4096+j]; }
  else if(l==1) v=bih2[j]+bhh2[j];
  else v=bih3[j]+bhh3[j];
  bias[idx]=v;
}

// P1 = [We(72 rows); Whh1(1024 rows)] -> bf16 [1096][4096]
__global__ __launch_bounds__(256) void k_pack1(const float* __restrict__ We, const float* __restrict__ Whh1, unsigned short* __restrict__ P1){
  size_t idx=(size_t)blockIdx.x*256+threadIdx.x; // exactly 1096*4096
  float v=(idx<(size_t)72*4096)? We[idx] : Whh1[idx-(size_t)72*4096];
  P1[idx]=f2bf(v);
}
// P = [A(1024 rows); B(1024 rows)] -> bf16 [2048][4096]
__global__ __launch_bounds__(256) void k_pack2(const float* __restrict__ A, const float* __restrict__ B, unsigned short* __restrict__ P){
  size_t idx=(size_t)blockIdx.x*256+threadIdx.x; // exactly 2048*4096
  float v=(idx<(size_t)1024*4096)? A[idx] : B[idx-(size_t)1024*4096];
  P[idx]=f2bf(v);
}

// ---------------- encoder ----------------

// x[row][j] = src[row]@enc_emb_W + b + pos(row%S)  ; 8 rows/block
__global__ __launch_bounds__(256) void k_embed(const float* __restrict__ src, const float* __restrict__ W,
    const float* __restrict__ bias, const float* __restrict__ posb, float* __restrict__ xout){
  __shared__ float s[8][438];
  int row0=blockIdx.x*8, tid=threadIdx.x;
  for(int idx=tid; idx<8*438; idx+=256){ int r=idx/438,k=idx%438; s[r][k]=src[(size_t)(row0+r)*438+k]; }
  __syncthreads();
  int j=tid; if(j<200){
    float acc[8];
    #pragma unroll
    for(int r=0;r<8;r++){ int t=(row0+r)%SQ; acc[r]=bias[j]+posb[t*200+j]; }
    for(int k=0;k<438;k++){
      float w=W[(size_t)k*200+j];
      #pragma unroll
      for(int r=0;r<8;r++) acc[r]+=s[r][k]*w;
    }
    for(int r=0;r<8;r++) xout[(size_t)(row0+r)*200+j]=acc[r];
  }
}

// generic 8-rows/block GEMM: out = A[rows,K]@W[K,N]+b (optional relu)
template<int K,int N,int CPT,bool RELU>
__global__ __launch_bounds__(256) void k_gemm8(const float* __restrict__ A, const float* __restrict__ W,
    const float* __restrict__ bias, float* __restrict__ out){
  __shared__ float s[8][K];
  int row0=blockIdx.x*8, tid=threadIdx.x;
  for(int idx=tid; idx<8*K; idx+=256){ int r=idx/K,k=idx%K; s[r][k]=A[(size_t)(row0+r)*K+k]; }
  __syncthreads();
  int j0=tid*CPT;
  float acc[8][CPT];
  #pragma unroll
  for(int r=0;r<8;r++)
    #pragma unroll
    for(int c=0;c<CPT;c++) acc[r][c]=bias[j0+c];
  for(int k=0;k<K;k++){
    float w[CPT];
    #pragma unroll
    for(int c=0;c<CPT;c++) w[c]=W[(size_t)k*N+j0+c];
    #pragma unroll
    for(int r=0;r<8;r++){ float a=s[r][k];
      #pragma unroll
      for(int c=0;c<CPT;c++) acc[r][c]+=a*w[c];
    }
  }
  #pragma unroll
  for(int r=0;r<8;r++)
    #pragma unroll
    for(int c=0;c<CPT;c++){ float v=acc[r][c]; if(RELU) v=fmaxf(v,0.f); out[(size_t)(row0+r)*N+j0+c]=v; }
}

// banded attention: grid (b,h,itile of 8); q,k,v in [B*S][512] (col = h*64+d)
__global__ __launch_bounds__(256) void k_attn(const float* __restrict__ Q, const float* __restrict__ Km,
    const float* __restrict__ V, float* __restrict__ O){
  int bid=blockIdx.x;
  int it=bid%225; int h=(bid/225)&7; int b=bid/1800;
  int i0=it*8;
  int j0=i0-100; if(j0<0) j0=0;
  int j1=i0+7+101; if(j1>SQ) j1=SQ;
  int JN=j1-j0; // <= 208
  __shared__ unsigned short kld[208][66];
  __shared__ unsigned short vld[208][66];
  __shared__ float q[8][64];
  __shared__ float sc[8][208];
  int tid=threadIdx.x;
  for(int idx=tid; idx<JN*64; idx+=256){
    int j=idx>>6, d=idx&63;
    size_t src=((size_t)(b*SQ+j0+j)*8+h)*64+d;
    kld[j][d]=f2bf(Km[src]);
    vld[j][d]=f2bf(V[src]);
  }
  for(int idx=tid; idx<8*64; idx+=256){ int r=idx>>6,d=idx&63; q[r][d]=Q[((size_t)(b*SQ+i0+r)*8+h)*64+d]; }
  __syncthreads();
  // scores
  {
    int r=tid>>5, js=tid&31;
    int i=i0+r;
    for(int j=js;j<JN;j+=32){
      int jg=j0+j; int diff=i-jg; if(diff<0) diff=-diff;
      float s=-1e30f;
      if(diff<=100){
        s=0.f;
        for(int d=0;d<64;d++) s+=q[r][d]*bf2f(kld[j][d]);
        s*=0.125f;
      }
      sc[r][j]=s;
    }
  }
  __syncthreads();
  // softmax (wave per 2 rows)
  {
    int wv=tid>>6, lane=tid&63;
    for(int rr=wv*2; rr<wv*2+2; rr++){
      float m=-1e30f;
      for(int j=lane;j<JN;j+=64) m=fmaxf(m,sc[rr][j]);
      for(int o=32;o;o>>=1) m=fmaxf(m,__shfl_xor(m,o));
      float sum=0.f;
      for(int j=lane;j<JN;j+=64){ float e=__expf(sc[rr][j]-m); sc[rr][j]=e; sum+=e; }
      for(int o=32;o;o>>=1) sum+=__shfl_xor(sum,o);
      float inv=1.f/sum;
      for(int j=lane;j<JN;j+=64) sc[rr][j]*=inv;
    }
  }
  __syncthreads();
  // PV
  {
    int d=tid&63, rb=tid>>6;
    for(int rr=rb; rr<8; rr+=4){
      float acc=0.f;
      for(int j=0;j<JN;j++) acc+=sc[rr][j]*bf2f(vld[j][d]);
      O[((size_t)(b*SQ+i0+rr)*8+h)*64+d]=acc;
    }
  }
}

// out-proj + residual + layernorm (in-place on x): x = LN(A@W + b + x)*g + bt
template<int K>
__global__ __launch_bounds__(256) void k_matln(const float* __restrict__ A, const float* __restrict__ W,
    const float* __restrict__ bias, const float* __restrict__ g, const float* __restrict__ bt, float* __restrict__ x){
  __shared__ float s[8][K];
  __shared__ float y[8][200];
  int row0=blockIdx.x*8, tid=threadIdx.x;
  for(int idx=tid; idx<8*K; idx+=256){ int r=idx/K,k=idx%K; s[r][k]=A[(size_t)(row0+r)*K+k]; }
  __syncthreads();
  if(tid<200){
    int j=tid;
    float acc[8];
    #pragma unroll
    for(int r=0;r<8;r++) acc[r]=bias[j];
    for(int k=0;k<K;k++){
      float w=W[(size_t)k*200+j];
      #pragma unroll
      for(int r=0;r<8;r++) acc[r]+=s[r][k]*w;
    }
    #pragma unroll
    for(int r=0;r<8;r++) y[r][j]=acc[r]+x[(size_t)(row0+r)*200+j];
  }
  __syncthreads();
  int wv=tid>>6, lane=tid&63;
  for(int rr=wv*2; rr<wv*2+2; rr++){
    float sm=0.f,s2=0.f;
    for(int j=lane;j<200;j+=64){ float v=y[rr][j]; sm+=v; s2+=v*v; }
    for(int o=32;o;o>>=1){ sm+=__shfl_xor(sm,o); s2+=__shfl_xor(s2,o); }
    float mean=sm*(1.f/200.f);
    float var=s2*(1.f/200.f)-mean*mean;
    float inv=rsqrtf(var+1e-5f);
    for(int j=lane;j<200;j+=64) x[(size_t)(row0+rr)*200+j]=(y[rr][j]-mean)*inv*g[j]+bt[j];
  }
}

// enc_part[b][t][j] = enc[b][t]@out_W[1024:] + out_b   (grid: t)
__global__ __launch_bounds__(320) void k_encpart(const float* __restrict__ x, const float* __restrict__ outW,
    const float* __restrict__ outb, float* __restrict__ ep){
  int t=blockIdx.x, tid=threadIdx.x;
  __shared__ float el[4][200];
  for(int idx=tid; idx<800; idx+=320){ int b=idx/200,k=idx%200; el[b][k]=x[((size_t)b*SQ+t)*200+k]; }
  __syncthreads();
  if(tid<288){
    int b=tid/72, j=tid%72;
    float acc=outb[j];
    for(int k=0;k<200;k++) acc+=el[b][k]*outW[(size_t)(1024+k)*72+j];
    ep[((size_t)b*SQ+t)*72+j]=acc;
  }
}

// ---------------- decoder step ----------------
// grid 544 blocks:
//  bid<32:    cell0 (cg=bid>>3, kc=bid&7,  chunk=137, K=1096=72(dec_in)+1024(h0))
//  bid<288:   cell1 (cg>>6,kc&63, chunk=32, K=2048=h0(1024)+h1(1024))
//  else:      cell2 (chunk=32, K=2048=h1+h2)
// Phase0 rebuilds the x-slice (pointwise LSTM recompute of step t-1 from gate partials),
// owners (cg==0, second part) persist c(t-1) and h2all. Phase1 streams bf16 weights and
// writes this step's gate partials.
__global__ __launch_bounds__(256) void k_dec_step(
    const unsigned short* __restrict__ P1, const unsigned short* __restrict__ P2, const unsigned short* __restrict__ P3,
    const float* __restrict__ bias, float* __restrict__ gpart, float* __restrict__ cbuf,
    const float* __restrict__ tgt, const float* __restrict__ bos, const float* __restrict__ h_init,
    const float* __restrict__ enc_part, const float* __restrict__ outW, float* __restrict__ h2all, int t)
{
  __shared__ __align__(16) float xs[137][4];
  __shared__ float h2s[4][1024];
  int bid=blockIdx.x, tid=threadIdx.x;
  int cell,cg,kc,chunkK;
  const unsigned short* P;
  if(bid<32){ cell=0; cg=bid>>3; kc=bid&7; chunkK=137; P=P1; }
  else if(bid<288){ int r=bid-32; cell=1; cg=r>>6; kc=r&63; chunkK=32; P=P2; }
  else { int r=bid-288; cell=2; cg=r>>6; kc=r&63; chunkK=32; P=P3; }
  int k0=kc*chunkK;
  int pg_prev=(t-1)&1, pg_cur=t&1;
  int pc_rd=t&1, pc_wr=(t-1)&1;
  bool fb=(t>0)&&(t%11==0);

  // feedback pre-pass: cell0/kc0 blocks rebuild full h2(t-1) for the out-projection
  if(cell==0 && kc==0 && fb){
    for(int idx=tid; idx<4096; idx+=256){
      int u=idx>>2, b=idx&3;
      int base=2*4096+u;
      float g0=bias[base],g1=bias[base+1024],g2=bias[base+2048],g3=bias[base+3072];
      for(int q=0;q<64;q++){
        const float* p=gpart+(((size_t)(pg_prev*64+q)*4+b)*12288+base);
        g0+=p[0]; g1+=p[1024]; g2+=p[2048]; g3+=p[3072];
      }
      float cp=cbuf[((size_t)(pc_rd*3+2)*4+b)*1024+u];
      float cn=sigm(g1)*cp+sigm(g0)*tanhf(g2);
      h2s[b][u]=sigm(g3)*tanhf(cn);
    }
    __syncthreads();
  }

  // phase 0: build x slice
  for(int idx=tid; idx<chunkK*4; idx+=256){
    int kk=idx>>2, b=idx&3; int kg=k0+kk;
    float xv=0.f;
    int lp=-1,u=0;
    if(cell==0){
      if(kg<72){
        if(t==0) xv=bos[b*72+kg];
        else if(t%11!=0) xv=tgt[((size_t)b*SQ+t)*72+kg];
        else {
          float acc=enc_part[((size_t)b*SQ+(t-1))*72+kg];
          for(int uu=0;uu<1024;uu++) acc+=h2s[b][uu]*outW[(size_t)uu*72+kg];
          xv=acc;
        }
      } else { lp=0; u=kg-72; }
    } else if(cell==1){ lp=(kg<1024)?0:1; u=kg&1023; }
    else { lp=(kg<1024)?1:2; u=kg&1023; }
    if(lp>=0){
      if(t==0){ xv=h_init[((size_t)lp*4+b)*1024+u]; }
      else {
        int nch=(lp==0)?8:64;
        int base=lp*4096+u;
        float g0=bias[base],g1=bias[base+1024],g2=bias[base+2048],g3=bias[base+3072];
        for(int q=0;q<nch;q++){
          const float* p=gpart+(((size_t)(pg_prev*64+q)*4+b)*12288+base);
          g0+=p[0]; g1+=p[1024]; g2+=p[2048]; g3+=p[3072];
        }
        float cp=cbuf[((size_t)(pc_rd*3+lp)*4+b)*1024+u];
        float cn=sigm(g1)*cp+sigm(g0)*tanhf(g2);
        float hn=sigm(g3)*tanhf(cn);
        xv=hn;
        bool owner=(cg==0)&&((cell==0)?(kg>=72):(kg>=1024));
        if(owner){
          cbuf[((size_t)(pc_wr*3+lp)*4+b)*1024+u]=cn;
          if(cell==2) h2all[((size_t)(t-1)*4+b)*1024+u]=hn;
        }
      }
    }
    xs[kk][b]=xv;
  }
  __syncthreads();

  // phase 1: stream weights, accumulate 4 cols x 4 batches
  int col0=cg*1024+tid*4;
  float4 acc0={0,0,0,0},acc1={0,0,0,0},acc2={0,0,0,0},acc3={0,0,0,0};
  const unsigned short* Pp=P+((size_t)k0*4096+col0);
  #pragma unroll 8
  for(int k=0;k<chunkK;k++){
    ushort4 w4=*(const ushort4*)(Pp+(size_t)k*4096);
    float w0=bf2f(w4.x),w1=bf2f(w4.y),w2=bf2f(w4.z),w3=bf2f(w4.w);
    float4 xv=*(const float4*)(&xs[k][0]);
    acc0.x+=w0*xv.x; acc0.y+=w1*xv.x; acc0.z+=w2*xv.x; acc0.w+=w3*xv.x;
    acc1.x+=w0*xv.y; acc1.y+=w1*xv.y; acc1.z+=w2*xv.y; acc1.w+=w3*xv.y;
    acc2.x+=w0*xv.z; acc2.y+=w1*xv.z; acc2.z+=w2*xv.z; acc2.w+=w3*xv.z;
    acc3.x+=w0*xv.w; acc3.y+=w1*xv.w; acc3.z+=w2*xv.w; acc3.w+=w3*xv.w;
  }
  size_t gb=((size_t)(pg_cur*64+kc)*4)*12288 + cell*4096 + col0;
  *(float4*)(gpart+gb)          =acc0;
  *(float4*)(gpart+gb+12288)    =acc1;
  *(float4*)(gpart+gb+2*12288)  =acc2;
  *(float4*)(gpart+gb+3*12288)  =acc3;
}

// materialize h2(1799) from the last step's partials
__global__ __launch_bounds__(256) void k_final_h2(const float* __restrict__ gpart, const float* __restrict__ cbuf,
    const float* __restrict__ bias, float* __restrict__ h2all){
  int idx=blockIdx.x*256+threadIdx.x; if(idx>=4096) return;
  int u=idx>>2, b=idx&3;
  const int t=SQ; // pseudo step 1800
  int pg_prev=(t-1)&1; int pc_rd=t&1;
  int base=2*4096+u;
  float g0=bias[base],g1=bias[base+1024],g2=bias[base+2048],g3=bias[base+3072];
  for(int q=0;q<64;q++){
    const float* p=gpart+(((size_t)(pg_prev*64+q)*4+b)*12288+base);
    g0+=p[0]; g1+=p[1024]; g2+=p[2048]; g3+=p[3072];
  }
  float cp=cbuf[((size_t)(pc_rd*3+2)*4+b)*1024+u];
  float cn=sigm(g1)*cp+sigm(g0)*tanhf(g2);
  float hn=sigm(g3)*tanhf(cn);
  h2all[((size_t)(t-1)*4+b)*1024+u]=hn;
}

// final: out[b][t][j] = h2all[t][b]@out_W[:1024] + enc_part[b][t][j]   (grid: t)
__global__ __launch_bounds__(320) void k_out(const float* __restrict__ h2all, const float* __restrict__ outW,
    const float* __restrict__ enc_part, float* __restrict__ out){
  int t=blockIdx.x, tid=threadIdx.x;
  __shared__ float h2l[4][1024];
  for(int idx=tid; idx<4096; idx+=320) h2l[idx>>10][idx&1023]=h2all[(size_t)t*4096+idx];
  __syncthreads();
  if(tid<288){
    int b=tid/72, j=tid%72;
    float acc=enc_part[((size_t)b*SQ+t)*72+j];
    for(int u=0;u<1024;u++) acc+=h2l[b][u]*outW[(size_t)u*72+j];
    out[((size_t)b*SQ+t)*72+j]=acc;
  }
}

// ---------------- host ----------------
extern "C" void kernel_launch(void* const* d_in, const int* in_sizes, int n_in,
                              void* d_out, int out_size, void* d_ws, size_t ws_size,
                              hipStream_t stream) {
  (void)in_sizes; (void)n_in; (void)out_size; (void)ws_size;
  const float* src   =(const float*)d_in[0];
  const float* tgt   =(const float*)d_in[1];
  const float* bos   =(const float*)d_in[2];
  const float* h_init=(const float*)d_in[3];
  const float* c_init=(const float*)d_in[4];
  const float* eW    =(const float*)d_in[6];
  const float* eb    =(const float*)d_in[7];
  const float* Wq    =(const float*)d_in[8];
  const float* bq    =(const float*)d_in[9];
  const float* Wk    =(const float*)d_in[10];
  const float* bk    =(const float*)d_in[11];
  const float* Wv    =(const float*)d_in[12];
  const float* bv    =(const float*)d_in[13];
  const float* Wo    =(const float*)d_in[14];
  const float* bo    =(const float*)d_in[15];
  const float* ln1g  =(const float*)d_in[16];
  const float* ln1b  =(const float*)d_in[17];
  const float* W1    =(const float*)d_in[18];
  const float* b1    =(const float*)d_in[19];
  const float* W2    =(const float*)d_in[20];
  const float* b2    =(const float*)d_in[21];
  const float* ln2g  =(const float*)d_in[22];
  const float* ln2b  =(const float*)d_in[23];
  const float* tgtW  =(const float*)d_in[24];
  const float* tgtb  =(const float*)d_in[25];
  const float* Wih1  =(const float*)d_in[26];
  const float* Whh1  =(const float*)d_in[27];
  const float* bih1  =(const float*)d_in[28];
  const float* bhh1  =(const float*)d_in[29];
  const float* Wih2  =(const float*)d_in[30];
  const float* Whh2  =(const float*)d_in[31];
  const float* bih2  =(const float*)d_in[32];
  const float* bhh2  =(const float*)d_in[33];
  const float* Wih3  =(const float*)d_in[34];
  const float* Whh3  =(const float*)d_in[35];
  const float* bih3  =(const float*)d_in[36];
  const float* bhh3  =(const float*)d_in[37];
  const float* outW  =(const float*)d_in[38];
  const float* outb  =(const float*)d_in[39];
  float* out=(float*)d_out;

  char* wsb=(char*)d_ws; size_t off=0;
  auto alloc=[&](size_t bytes)->void*{ void* p=wsb+off; off+=(bytes+255)&~(size_t)255; return p; };
  unsigned short* P1=(unsigned short*)alloc((size_t)1096*4096*2);
  unsigned short* P2=(unsigned short*)alloc((size_t)2048*4096*2);
  unsigned short* P3=(unsigned short*)alloc((size_t)2048*4096*2);
  float* We   =(float*)alloc((size_t)72*4096*4);
  float* bias =(float*)alloc((size_t)3*4096*4);
  float* cbuf =(float*)alloc((size_t)2*3*4*1024*4);
  float* gpart=(float*)alloc((size_t)2*64*4*12288*4);
  float* encp =(float*)alloc((size_t)7200*72*4);
  float* posb =(float*)alloc((size_t)SQ*200*4);
  float* xb   =(float*)alloc((size_t)7200*200*4);
  float* qb   =(float*)alloc((size_t)7200*512*4);
  float* kb   =(float*)alloc((size_t)7200*512*4);
  float* vb   =(float*)alloc((size_t)7200*512*4);
  float* ob   =(float*)alloc((size_t)7200*512*4);
  float* h2all=qb;   // alias: q+k region (dead after encoder) = 29.49MB
  float* mid  =vb;   // alias: v+o region (dead before FFN)   = 29.49MB
  (void)kb; (void)ob;

  // c(-1) = c_init into parity-1 slot of cbuf
  hipMemcpyAsync(cbuf+3*4*1024, c_init, (size_t)3*4*1024*4, hipMemcpyDeviceToDevice, stream);

  // prep
  k_postab<<<(SQ*200+255)/256,256,0,stream>>>(posb);
  k_we<<<72*4096/256,256,0,stream>>>(tgtW,Wih1,We);
  k_bias<<<48,256,0,stream>>>(tgtb,Wih1,bih1,bhh1,bih2,bhh2,bih3,bhh3,bias);
  k_pack1<<<1096*4096/256,256,0,stream>>>(We,Whh1,P1);
  k_pack2<<<2048*4096/256,256,0,stream>>>(Wih2,Whh2,P2);
  k_pack2<<<2048*4096/256,256,0,stream>>>(Wih3,Whh3,P3);

  // encoder
  k_embed<<<900,256,0,stream>>>(src,eW,eb,posb,xb);
  for(int l=0;l<2;l++){
    k_gemm8<200,512,2,false><<<900,256,0,stream>>>(xb,Wq+(size_t)l*200*512,bq+l*512,qb);
    k_gemm8<200,512,2,false><<<900,256,0,stream>>>(xb,Wk+(size_t)l*200*512,bk+l*512,kb);
    k_gemm8<200,512,2,false><<<900,256,0,stream>>>(xb,Wv+(size_t)l*200*512,bv+l*512,vb);
    k_attn<<<7200,256,0,stream>>>(qb,kb,vb,ob);
    k_matln<512><<<900,256,0,stream>>>(ob,Wo+(size_t)l*512*200,bo+l*200,ln1g+l*200,ln1b+l*200,xb);
    k_gemm8<200,1024,4,true><<<900,256,0,stream>>>(xb,W1+(size_t)l*200*1024,b1+l*1024,mid);
    k_matln<1024><<<900,256,0,stream>>>(mid,W2+(size_t)l*1024*200,b2+l*200,ln2g+l*200,ln2b+l*200,xb);
  }
  k_encpart<<<SQ,320,0,stream>>>(xb,outW,outb,encp);

  // serial decoder
  for(int t=0;t<SQ;t++)
    k_dec_step<<<544,256,0,stream>>>(P1,P2,P3,bias,gpart,cbuf,tgt,bos,h_init,encp,outW,h2all,t);
  k_final_h2<<<16,256,0,stream>>>(gpart,cbuf,bias,h2all);
  k_out<<<SQ,320,0,stream>>>(h2all,outW,encp,out);
}

// Round 2
// 22905.792 us; speedup vs baseline: 3.6707x; 3.6707x over previous
//
#include <hip/hip_runtime.h>

#define SQ 1800
#define NBLK 256

typedef _Float16 h2v __attribute__((ext_vector_type(2)));
#define AGT __HIP_MEMORY_SCOPE_AGENT

__device__ __forceinline__ float bf2f(unsigned short u){ return __uint_as_float(((unsigned)u)<<16); }
__device__ __forceinline__ unsigned short f2bf(float f){
  unsigned u=__float_as_uint(f);
  unsigned r=u+0x7FFFu+((u>>16)&1u);
  return (unsigned short)(r>>16);
}
__device__ __forceinline__ float sigm(float x){ return 1.0f/(1.0f+__expf(-x)); }
__device__ __forceinline__ unsigned pack16(float a, float b){
  _Float16 ha=(_Float16)a, hb=(_Float16)b;
  unsigned short ua=__builtin_bit_cast(unsigned short,ha), ub=__builtin_bit_cast(unsigned short,hb);
  return (unsigned)ua | ((unsigned)ub<<16);
}
__device__ __forceinline__ float lo16(unsigned v){ h2v h=__builtin_bit_cast(h2v,v); return (float)h[0]; }
__device__ __forceinline__ float hi16(unsigned v){ h2v h=__builtin_bit_cast(h2v,v); return (float)h[1]; }
__device__ __forceinline__ float hdot2(unsigned uw, unsigned ux, float acc){
  h2v a=__builtin_bit_cast(h2v,uw), b=__builtin_bit_cast(h2v,ux);
#if __has_builtin(__builtin_amdgcn_fdot2)
  return __builtin_amdgcn_fdot2(a,b,acc,false);
#else
  return acc + (float)a[0]*(float)b[0] + (float)a[1]*(float)b[1];
#endif
}
__device__ __forceinline__ unsigned aload(const unsigned* p){
  return __hip_atomic_load(p,__ATOMIC_RELAXED,AGT);
}
__device__ __forceinline__ void astore(unsigned* p, unsigned v){
  __hip_atomic_store(p,v,__ATOMIC_RELAXED,AGT);
}

// ---------------- prep kernels ----------------

__global__ __launch_bounds__(256) void k_postab(float* __restrict__ pt){
  int idx=blockIdx.x*256+threadIdx.x; if(idx>=SQ*200) return;
  int t=idx/200, j=idx%200;
  double ang=(double)(t+1)*pow(10000.0, -(double)(2*(j/2))/200.0);
  pt[idx]=(float)((j&1)? cos(ang) : sin(ang));
}

// W_e[k][j] = sum_m tgt_W[k][m] * Wih1[m][j]   (72 x 4096)
__global__ __launch_bounds__(256) void k_we(const float* __restrict__ tgtW, const float* __restrict__ Wih1, float* __restrict__ We){
  int idx=blockIdx.x*256+threadIdx.x;
  int k=idx>>12, j=idx&4095;
  float acc=0.f;
  for(int m=0;m<200;m++) acc+=tgtW[k*200+m]*Wih1[(size_t)m*4096+j];
  We[idx]=acc;
}

// bias[3][4096]
__global__ __launch_bounds__(256) void k_bias(const float* __restrict__ tgtb, const float* __restrict__ Wih1,
    const float* __restrict__ bih1,const float* __restrict__ bhh1,const float* __restrict__ bih2,const float* __restrict__ bhh2,
    const float* __restrict__ bih3,const float* __restrict__ bhh3,float* __restrict__ bias){
  int idx=blockIdx.x*256+threadIdx.x; if(idx>=3*4096) return;
  int l=idx>>12, j=idx&4095;
  float v;
  if(l==0){ v=bih1[j]+bhh1[j]; for(int m=0;m<200;m++) v+=tgtb[m]*Wih1[(size_t)m*4096+j]; }
  else if(l==1) v=bih2[j]+bhh2[j];
  else v=bih3[j]+bhh3[j];
  bias[idx]=v;
}

// packed f16 weights, unit-major [cell][u][k2][4gates] with per-unit k2 padding
// cell0: 576 k2 (K=1096 real), stride 2304 u32 ; cell1/2: 1056 k2 (K=2048), stride 4224 u32
__global__ __launch_bounds__(256) void k_packf(const float* __restrict__ We, const float* __restrict__ Whh1,
  const float* __restrict__ Wih2, const float* __restrict__ Whh2,
  const float* __restrict__ Wih3, const float* __restrict__ Whh3, unsigned* __restrict__ P){
  size_t idx=(size_t)blockIdx.x*256+threadIdx.x; // exactly 11,010,048
  const float *A, *Bm; size_t l; int stride, KA, K;
  if(idx < 2359296u){ l=idx; stride=2304; A=We; Bm=Whh1; KA=72; K=1096; }
  else if(idx < 6684672u){ l=idx-2359296u; stride=4224; A=Wih2; Bm=Whh2; KA=1024; K=2048; }
  else { l=idx-6684672u; stride=4224; A=Wih3; Bm=Whh3; KA=1024; K=2048; }
  int u=(int)(l/(size_t)stride); int r=(int)(l-(size_t)u*stride);
  int k2=r>>2, g=r&3, k=2*k2;
  float w0=0.f,w1=0.f;
  if(k<K){
    int col=g*1024+u;
    w0 = (k   < KA)? A[(size_t)k*4096+col]      : Bm[(size_t)(k-KA)*4096+col];
    w1 = (k+1 < KA)? A[(size_t)(k+1)*4096+col]  : Bm[(size_t)(k+1-KA)*4096+col];
  }
  P[idx]=pack16(w0,w1);
}

// outWT[j][u] = out_W[u][j] for u<1024 (h2 part), [72][1024]
__global__ __launch_bounds__(256) void k_outwt(const float* __restrict__ outW, float* __restrict__ outWT){
  int idx=blockIdx.x*256+threadIdx.x; if(idx>=72*1024) return;
  int j=idx>>10, u=idx&1023;
  outWT[idx]=outW[(size_t)u*72+j];
}

// ---------------- encoder ----------------

__global__ __launch_bounds__(256) void k_embed(const float* __restrict__ src, const float* __restrict__ W,
    const float* __restrict__ bias, const float* __restrict__ posb, float* __restrict__ xout){
  __shared__ float s[8][438];
  int row0=blockIdx.x*8, tid=threadIdx.x;
  for(int idx=tid; idx<8*438; idx+=256){ int r=idx/438,k=idx%438; s[r][k]=src[(size_t)(row0+r)*438+k]; }
  __syncthreads();
  int j=tid; if(j<200){
    float acc[8];
    #pragma unroll
    for(int r=0;r<8;r++){ int t=(row0+r)%SQ; acc[r]=bias[j]+posb[t*200+j]; }
    for(int k=0;k<438;k++){
      float w=W[(size_t)k*200+j];
      #pragma unroll
      for(int r=0;r<8;r++) acc[r]+=s[r][k]*w;
    }
    for(int r=0;r<8;r++) xout[(size_t)(row0+r)*200+j]=acc[r];
  }
}

template<int K,int N,int CPT,bool RELU>
__global__ __launch_bounds__(256) void k_gemm8(const float* __restrict__ A, const float* __restrict__ W,
    const float* __restrict__ bias, float* __restrict__ out){
  __shared__ float s[8][K];
  int row0=blockIdx.x*8, tid=threadIdx.x;
  for(int idx=tid; idx<8*K; idx+=256){ int r=idx/K,k=idx%K; s[r][k]=A[(size_t)(row0+r)*K+k]; }
  __syncthreads();
  int j0=tid*CPT;
  float acc[8][CPT];
  #pragma unroll
  for(int r=0;r<8;r++)
    #pragma unroll
    for(int c=0;c<CPT;c++) acc[r][c]=bias[j0+c];
  for(int k=0;k<K;k++){
    float w[CPT];
    #pragma unroll
    for(int c=0;c<CPT;c++) w[c]=W[(size_t)k*N+j0+c];
    #pragma unroll
    for(int r=0;r<8;r++){ float a=s[r][k];
      #pragma unroll
      for(int c=0;c<CPT;c++) acc[r][c]+=a*w[c];
    }
  }
  #pragma unroll
  for(int r=0;r<8;r++)
    #pragma unroll
    for(int c=0;c<CPT;c++){ float v=acc[r][c]; if(RELU) v=fmaxf(v,0.f); out[(size_t)(row0+r)*N+j0+c]=v; }
}

__global__ __launch_bounds__(256) void k_attn(const float* __restrict__ Q, const float* __restrict__ Km,
    const float* __restrict__ V, float* __restrict__ O){
  int bid=blockIdx.x;
  int it=bid%225; int h=(bid/225)&7; int b=bid/1800;
  int i0=it*8;
  int j0=i0-100; if(j0<0) j0=0;
  int j1=i0+7+101; if(j1>SQ) j1=SQ;
  int JN=j1-j0;
  __shared__ unsigned short kld[208][66];
  __shared__ unsigned short vld[208][66];
  __shared__ float q[8][64];
  __shared__ float sc[8][208];
  int tid=threadIdx.x;
  for(int idx=tid; idx<JN*64; idx+=256){
    int j=idx>>6, d=idx&63;
    size_t src=((size_t)(b*SQ+j0+j)*8+h)*64+d;
    kld[j][d]=f2bf(Km[src]);
    vld[j][d]=f2bf(V[src]);
  }
  for(int idx=tid; idx<8*64; idx+=256){ int r=idx>>6,d=idx&63; q[r][d]=Q[((size_t)(b*SQ+i0+r)*8+h)*64+d]; }
  __syncthreads();
  {
    int r=tid>>5, js=tid&31;
    int i=i0+r;
    for(int j=js;j<JN;j+=32){
      int jg=j0+j; int diff=i-jg; if(diff<0) diff=-diff;
      float s=-1e30f;
      if(diff<=100){
        s=0.f;
        for(int d=0;d<64;d++) s+=q[r][d]*bf2f(kld[j][d]);
        s*=0.125f;
      }
      sc[r][j]=s;
    }
  }
  __syncthreads();
  {
    int wv=tid>>6, lane=tid&63;
    for(int rr=wv*2; rr<wv*2+2; rr++){
      float m=-1e30f;
      for(int j=lane;j<JN;j+=64) m=fmaxf(m,sc[rr][j]);
      for(int o=32;o;o>>=1) m=fmaxf(m,__shfl_xor(m,o));
      float sum=0.f;
      for(int j=lane;j<JN;j+=64){ float e=__expf(sc[rr][j]-m); sc[rr][j]=e; sum+=e; }
      for(int o=32;o;o>>=1) sum+=__shfl_xor(sum,o);
      float inv=1.f/sum;
      for(int j=lane;j<JN;j+=64) sc[rr][j]*=inv;
    }
  }
  __syncthreads();
  {
    int d=tid&63, rb=tid>>6;
    for(int rr=rb; rr<8; rr+=4){
      float acc=0.f;
      for(int j=0;j<JN;j++) acc+=sc[rr][j]*bf2f(vld[j][d]);
      O[((size_t)(b*SQ+i0+rr)*8+h)*64+d]=acc;
    }
  }
}

template<int K>
__global__ __launch_bounds__(256) void k_matln(const float* __restrict__ A, const float* __restrict__ W,
    const float* __restrict__ bias, const float* __restrict__ g, const float* __restrict__ bt, float* __restrict__ x){
  __shared__ float s[8][K];
  __shared__ float y[8][200];
  int row0=blockIdx.x*8, tid=threadIdx.x;
  for(int idx=tid; idx<8*K; idx+=256){ int r=idx/K,k=idx%K; s[r][k]=A[(size_t)(row0+r)*K+k]; }
  __syncthreads();
  if(tid<200){
    int j=tid;
    float acc[8];
    #pragma unroll
    for(int r=0;r<8;r++) acc[r]=bias[j];
    for(int k=0;k<K;k++){
      float w=W[(size_t)k*200+j];
      #pragma unroll
      for(int r=0;r<8;r++) acc[r]+=s[r][k]*w;
    }
    #pragma unroll
    for(int r=0;r<8;r++) y[r][j]=acc[r]+x[(size_t)(row0+r)*200+j];
  }
  __syncthreads();
  int wv=tid>>6, lane=tid&63;
  for(int rr=wv*2; rr<wv*2+2; rr++){
    float sm=0.f,s2=0.f;
    for(int j=lane;j<200;j+=64){ float v=y[rr][j]; sm+=v; s2+=v*v; }
    for(int o=32;o;o>>=1){ sm+=__shfl_xor(sm,o); s2+=__shfl_xor(s2,o); }
    float mean=sm*(1.f/200.f);
    float var=s2*(1.f/200.f)-mean*mean;
    float inv=rsqrtf(var+1e-5f);
    for(int j=lane;j<200;j+=64) x[(size_t)(row0+rr)*200+j]=(y[rr][j]-mean)*inv*g[j]+bt[j];
  }
}

__global__ __launch_bounds__(320) void k_encpart(const float* __restrict__ x, const float* __restrict__ outW,
    const float* __restrict__ outb, float* __restrict__ ep){
  int t=blockIdx.x, tid=threadIdx.x;
  __shared__ float el[4][200];
  for(int idx=tid; idx<800; idx+=320){ int b=idx/200,k=idx%200; el[b][k]=x[((size_t)b*SQ+t)*200+k]; }
  __syncthreads();
  if(tid<288){
    int b=tid/72, j=tid%72;
    float acc=outb[j];
    for(int k=0;k<200;k++) acc+=el[b][k]*outW[(size_t)(1024+k)*72+j];
    ep[((size_t)b*SQ+t)*72+j]=acc;
  }
}

// ---------------- persistent decoder ----------------
// 256 blocks x 512 threads, 1 block/CU (LDS>80KB forces it). Block b owns
// u in {4b..4b+3} of each cell, full K in-block => no cross-block reduction.
// Weights live in VGPRs (t-invariant preload). One grid barrier per step
// (two on feedback steps). Cross-block h/fb data via relaxed agent atomics
// (sc-coherent, no L2-invalidating acquire fences).

__device__ __forceinline__ void gridbar(unsigned* bar, unsigned gen){
  __syncthreads();   // drains vmcnt per wave -> all h stores acked
  if(threadIdx.x==0){
    unsigned r=__hip_atomic_fetch_add(&bar[0],1u,__ATOMIC_RELAXED,AGT);
    if(r==gen*(unsigned)NBLK+(unsigned)(NBLK-1)){
      __hip_atomic_store(&bar[64],gen+1u,__ATOMIC_RELAXED,AGT);
    } else {
      unsigned f;
      do{ __builtin_amdgcn_s_sleep(2);
          f=__hip_atomic_load(&bar[64],__ATOMIC_RELAXED,AGT);
      }while(f<gen+1u);
    }
  }
  __syncthreads();
}

__global__ __launch_bounds__(512,2) void k_dec(
  const uint4* __restrict__ P4, const float* __restrict__ bias,
  unsigned* __restrict__ hbufU, unsigned* __restrict__ fbbufU,
  unsigned* __restrict__ h2allU, unsigned* __restrict__ bar,
  const float* __restrict__ tgt, const float* __restrict__ bos,
  const float* __restrict__ h_init, const float* __restrict__ c_init,
  const float* __restrict__ encp, const float* __restrict__ outWT)
{
  __shared__ __align__(16) unsigned xs2[2688*4]; // 43008 B, f16-pair x, [row][4 batches]
  __shared__ float red[16*513];                  // 32832 B padded partial sums
  __shared__ float gsum[192];
  __shared__ float c_lds[48];
  __shared__ float htmp[48];
  __shared__ float ldspad[1200];                 // force 1 block/CU (>80KB total)
  int tid=threadIdx.x, blk=blockIdx.x;
  if(tid==0) ldspad[0]=0.f;

  // thread -> (unit, k-split lane); wave-uniform category boundaries
  int uu, ks;
  if(tid<128){ uu=tid>>5; ks=tid&31; }
  else if(tid<320){ int l=tid-128; uu=4+l/48; ks=l-(uu-4)*48; }
  else { int l=tid-320; uu=8+l/48; ks=l-(uu-8)*48; }
  int cell = uu<4?0:(uu<8?1:2);
  int u_loc=uu&3, u_glob=blk*4+u_loc;
  size_t ubase4 = (cell==0)? (size_t)u_glob*576 :
                  (cell==1)? (589824u + (size_t)u_glob*1056) :
                             (1671168u + (size_t)u_glob*1056);
  int xoff = (cell==0)?0:(cell==1?576:1632);

  // t-invariant weight preload into VGPRs
  uint4 w[22];
  if(tid<128){
    #pragma unroll
    for(int i=0;i<18;i++) w[i]=P4[ubase4 + (size_t)ks + (size_t)i*32];
  } else {
    #pragma unroll
    for(int i=0;i<22;i++) w[i]=P4[ubase4 + (size_t)ks + (size_t)i*48];
  }

  // c state init (lives in LDS for all 1800 steps)
  if(tid<48){
    int uu0=tid>>2, b0=tid&3;
    int cl=uu0<4?0:(uu0<8?1:2);
    c_lds[tid]=c_init[((size_t)cl*4+b0)*1024 + (size_t)blk*4+(uu0&3)];
  }
  __syncthreads();

  unsigned gen=0;
  for(int t=0;t<SQ;t++){
    bool fb=(t>0)&&(t%11==0);
    if(fb){
      // blocks 0..71: dec_in(t) = h2(t-1) @ outW_h + encp(t-1)
      if(blk<72 && tid<256){
        int j=blk, b=tid>>6, lane=tid&63, pv=(t-1)&1;
        float s=0.f;
        #pragma unroll
        for(int q=0;q<8;q++){
          int u2=lane+q*64;
          unsigned v=aload(&hbufU[(size_t)((pv*3+2)*4+b)*512+u2]);
          s += lo16(v)*outWT[(size_t)j*1024+2*u2] + hi16(v)*outWT[(size_t)j*1024+2*u2+1];
        }
        #pragma unroll
        for(int o=32;o;o>>=1) s+=__shfl_xor(s,o);
        if(lane==0) astore(&fbbufU[b*72+j], __float_as_uint(s + encp[((size_t)b*SQ+(t-1))*72+j]));
      }
      gridbar(bar,gen); gen++;
    }

    // ---- stage x (f16 pairs) ----
    int pv=(t-1)&1;
    for(int r=tid;r<2688;r+=512){
      int cl, rr;
      if(r<576){cl=0;rr=r;} else if(r<1632){cl=1;rr=r-576;} else {cl=2;rr=r-1632;}
      unsigned v0=0u,v1=0u,v2=0u,v3=0u;
      #pragma unroll
      for(int b=0;b<4;b++){
        unsigned v=0u;
        if(cl==0){
          if(rr<36){
            int j=rr*2;
            if(t==0) v=pack16(bos[b*72+j],bos[b*72+j+1]);
            else if(fb) v=pack16(__uint_as_float(aload(&fbbufU[b*72+j])),
                                 __uint_as_float(aload(&fbbufU[b*72+j+1])));
            else { const float* p=&tgt[((size_t)b*SQ+t)*72+j]; v=pack16(p[0],p[1]); }
          } else if(rr<548){
            int pr=rr-36;
            if(t==0){ const float* p=&h_init[(size_t)b*1024+2*pr]; v=pack16(p[0],p[1]); }
            else v=aload(&hbufU[(size_t)((pv*3+0)*4+b)*512+pr]);
          }
        } else {
          int lp0 = (cl==1)?0:1;
          if(rr<512){
            if(t==0){ const float* p=&h_init[((size_t)lp0*4+b)*1024+2*rr]; v=pack16(p[0],p[1]); }
            else v=aload(&hbufU[(size_t)((pv*3+lp0)*4+b)*512+rr]);
          } else if(rr<1024){
            int pr=rr-512, lp1=lp0+1;
            if(t==0){ const float* p=&h_init[((size_t)lp1*4+b)*1024+2*pr]; v=pack16(p[0],p[1]); }
            else v=aload(&hbufU[(size_t)((pv*3+lp1)*4+b)*512+pr]);
          }
        }
        if(b==0)v0=v; else if(b==1)v1=v; else if(b==2)v2=v; else v3=v;
      }
      uint4 vv; vv.x=v0; vv.y=v1; vv.z=v2; vv.w=v3;
      *(uint4*)&xs2[(size_t)r*4]=vv;
    }
    __syncthreads();

    // ---- gates: acc[g*4+b] over this thread's k slice ----
    {
      float acc[16];
      #pragma unroll
      for(int a=0;a<16;a++) acc[a]=0.f;
      auto run=[&](int NIT,int NKS){
        #pragma unroll
        for(int i=0;i<22;i++){
          if(i>=NIT) break;
          const uint4 xv=*(const uint4*)&xs2[(size_t)(xoff+ks+i*NKS)*4];
          const unsigned* wu=(const unsigned*)&w[i];
          const unsigned* xu=(const unsigned*)&xv;
          #pragma unroll
          for(int g=0;g<4;g++)
            #pragma unroll
            for(int b=0;b<4;b++)
              acc[g*4+b]=hdot2(wu[g],xu[b],acc[g*4+b]);
        }
      };
      if(tid<128) run(18,32); else run(22,48);
      #pragma unroll
      for(int a=0;a<16;a++) red[a*513+tid]=acc[a];
    }
    __syncthreads();

    // ---- per-unit reduce + bias ----
    if(tid<192){
      int uuo=tid>>4, a=tid&15;
      int base,n;
      if(uuo<4){base=uuo*32;n=32;} else {base=128+(uuo-4)*48;n=48;}
      float s=0.f;
      for(int j2=0;j2<n;j2++) s+=red[a*513+base+j2];
      int cl=uuo<4?0:(uuo<8?1:2), g=a>>2;
      gsum[tid]=s+bias[(size_t)cl*4096+(size_t)g*1024+blk*4+(uuo&3)];
    }
    __syncthreads();

    // ---- pointwise LSTM ----
    if(tid<48){
      int uup=tid>>2,b=tid&3;
      float gi=gsum[uup*16+b],gf=gsum[uup*16+4+b],gg=gsum[uup*16+8+b],go=gsum[uup*16+12+b];
      float cp=c_lds[tid];
      float cn=sigm(gf)*cp+sigm(gi)*tanhf(gg);
      float hn=sigm(go)*tanhf(cn);
      c_lds[tid]=cn; htmp[tid]=hn;
    }
    __syncthreads();
    if(tid<48 && !(tid&4)){ // even unit: pack (u, u+1) pair
      int uup=tid>>2,b=tid&3;
      int cl=uup<4?0:(uup<8?1:2), ul=uup&3;
      unsigned v=pack16(htmp[tid],htmp[tid+4]);
      int upair=blk*2+(ul>>1);
      astore(&hbufU[(size_t)(((t&1)*3+cl)*4+b)*512+upair], v);
      if(cl==2) astore(&h2allU[((size_t)t*4+b)*512+upair], v);
    }
    gridbar(bar,gen); gen++;
  }
}

// final: out[b][t][j] = h2(t) @ out_W[:1024] + enc_part[b][t][j]
__global__ __launch_bounds__(320) void k_out(const unsigned* __restrict__ h2allU, const float* __restrict__ outW,
    const float* __restrict__ enc_part, float* __restrict__ out){
  int t=blockIdx.x, tid=threadIdx.x;
  __shared__ float h2l[4][1024];
  for(int idx=tid; idx<2048; idx+=320){
    int b=idx>>9, p=idx&511;
    unsigned v=h2allU[((size_t)t*4+b)*512+p];
    h2l[b][2*p]=lo16(v); h2l[b][2*p+1]=hi16(v);
  }
  __syncthreads();
  if(tid<288){
    int b=tid/72, j=tid%72;
    float acc=enc_part[((size_t)b*SQ+t)*72+j];
    for(int u=0;u<1024;u++) acc+=h2l[b][u]*outW[(size_t)u*72+j];
    out[((size_t)b*SQ+t)*72+j]=acc;
  }
}

// ---------------- host ----------------
extern "C" void kernel_launch(void* const* d_in, const int* in_sizes, int n_in,
                              void* d_out, int out_size, void* d_ws, size_t ws_size,
                              hipStream_t stream) {
  (void)in_sizes; (void)n_in; (void)out_size; (void)ws_size;
  const float* src   =(const float*)d_in[0];
  const float* tgt   =(const float*)d_in[1];
  const float* bos   =(const float*)d_in[2];
  const float* h_init=(const float*)d_in[3];
  const float* c_init=(const float*)d_in[4];
  const float* eW    =(const float*)d_in[6];
  const float* eb    =(const float*)d_in[7];
  const float* Wq    =(const float*)d_in[8];
  const float* bq    =(const float*)d_in[9];
  const float* Wk    =(const float*)d_in[10];
  const float* bk    =(const float*)d_in[11];
  const float* Wv    =(const float*)d_in[12];
  const float* bv    =(const float*)d_in[13];
  const float* Wo    =(const float*)d_in[14];
  const float* bo    =(const float*)d_in[15];
  const float* ln1g  =(const float*)d_in[16];
  const float* ln1b  =(const float*)d_in[17];
  const float* W1    =(const float*)d_in[18];
  const float* b1    =(const float*)d_in[19];
  const float* W2    =(const float*)d_in[20];
  const float* b2    =(const float*)d_in[21];
  const float* ln2g  =(const float*)d_in[22];
  const float* ln2b  =(const float*)d_in[23];
  const float* tgtW  =(const float*)d_in[24];
  const float* tgtb  =(const float*)d_in[25];
  const float* Wih1  =(const float*)d_in[26];
  const float* Whh1  =(const float*)d_in[27];
  const float* bih1  =(const float*)d_in[28];
  const float* bhh1  =(const float*)d_in[29];
  const float* Wih2  =(const float*)d_in[30];
  const float* Whh2  =(const float*)d_in[31];
  const float* bih2  =(const float*)d_in[32];
  const float* bhh2  =(const float*)d_in[33];
  const float* Wih3  =(const float*)d_in[34];
  const float* Whh3  =(const float*)d_in[35];
  const float* bih3  =(const float*)d_in[36];
  const float* bhh3  =(const float*)d_in[37];
  const float* outW  =(const float*)d_in[38];
  const float* outb  =(const float*)d_in[39];
  float* out=(float*)d_out;

  char* wsb=(char*)d_ws; size_t off=0;
  auto alloc=[&](size_t bytes)->void*{ void* p=wsb+off; off+=(bytes+255)&~(size_t)255; return p; };
  unsigned* Pf   =(unsigned*)alloc((size_t)11010048*4);   // 44.04 MB packed f16 weights
  float* We   =(float*)alloc((size_t)72*4096*4);
  float* bias =(float*)alloc((size_t)3*4096*4);
  float* outWT=(float*)alloc((size_t)72*1024*4);
  unsigned* hbufU =(unsigned*)alloc((size_t)2*3*4*512*4);
  unsigned* fbbufU=(unsigned*)alloc((size_t)4*72*4);
  unsigned* bar   =(unsigned*)alloc(512);
  float* encp =(float*)alloc((size_t)7200*72*4);
  float* posb =(float*)alloc((size_t)SQ*200*4);
  float* xb   =(float*)alloc((size_t)7200*200*4);
  float* qb   =(float*)alloc((size_t)7200*512*4);
  float* kb   =(float*)alloc((size_t)7200*512*4);
  float* vb   =(float*)alloc((size_t)7200*512*4);
  float* ob   =(float*)alloc((size_t)7200*512*4);
  unsigned* h2allU=(unsigned*)qb; // alias: dead after encoder; 1800*4*512*4B = 14.74MB fits
  float* mid  =vb;                // alias for FFN intermediate
  (void)kb; (void)ob;

  // prep
  k_postab<<<(SQ*200+255)/256,256,0,stream>>>(posb);
  k_we<<<72*4096/256,256,0,stream>>>(tgtW,Wih1,We);
  k_bias<<<48,256,0,stream>>>(tgtb,Wih1,bih1,bhh1,bih2,bhh2,bih3,bhh3,bias);
  k_packf<<<43008,256,0,stream>>>(We,Whh1,Wih2,Whh2,Wih3,Whh3,Pf);
  k_outwt<<<(72*1024+255)/256,256,0,stream>>>(outW,outWT);

  // encoder
  k_embed<<<900,256,0,stream>>>(src,eW,eb,posb,xb);
  for(int l=0;l<2;l++){
    k_gemm8<200,512,2,false><<<900,256,0,stream>>>(xb,Wq+(size_t)l*200*512,bq+l*512,qb);
    k_gemm8<200,512,2,false><<<900,256,0,stream>>>(xb,Wk+(size_t)l*200*512,bk+l*512,kb);
    k_gemm8<200,512,2,false><<<900,256,0,stream>>>(xb,Wv+(size_t)l*200*512,bv+l*512,vb);
    k_attn<<<7200,256,0,stream>>>(qb,kb,vb,ob);
    k_matln<512><<<900,256,0,stream>>>(ob,Wo+(size_t)l*512*200,bo+l*200,ln1g+l*200,ln1b+l*200,xb);
    k_gemm8<200,1024,4,true><<<900,256,0,stream>>>(xb,W1+(size_t)l*200*1024,b1+l*1024,mid);
    k_matln<1024><<<900,256,0,stream>>>(mid,W2+(size_t)l*1024*200,b2+l*200,ln2g+l*200,ln2b+l*200,xb);
  }
  k_encpart<<<SQ,320,0,stream>>>(xb,outW,outb,encp);

  // persistent decoder (single dispatch, grid barrier per step)
  hipMemsetAsync(bar,0,512,stream);
  k_dec<<<NBLK,512,0,stream>>>((const uint4*)Pf,bias,hbufU,fbbufU,h2allU,bar,
                               tgt,bos,h_init,c_init,encp,outWT);

  // output projection
  k_out<<<SQ,320,0,stream>>>(h2allU,outW,encp,out);
}

// Round 3
// 14735.097 us; speedup vs baseline: 5.7061x; 1.5545x over previous
//
#include <hip/hip_runtime.h>

#define SQ 1800
#define NBLK 256

typedef _Float16 h2v __attribute__((ext_vector_type(2)));
#define AGT __HIP_MEMORY_SCOPE_AGENT

__device__ __forceinline__ float bf2f(unsigned short u){ return __uint_as_float(((unsigned)u)<<16); }
__device__ __forceinline__ unsigned short f2bf(float f){
  unsigned u=__float_as_uint(f);
  unsigned r=u+0x7FFFu+((u>>16)&1u);
  return (unsigned short)(r>>16);
}
__device__ __forceinline__ float sigm(float x){ return 1.0f/(1.0f+__expf(-x)); }
__device__ __forceinline__ unsigned pack16(float a, float b){
  _Float16 ha=(_Float16)a, hb=(_Float16)b;
  unsigned short ua=__builtin_bit_cast(unsigned short,ha), ub=__builtin_bit_cast(unsigned short,hb);
  return (unsigned)ua | ((unsigned)ub<<16);
}
__device__ __forceinline__ float lo16(unsigned v){ h2v h=__builtin_bit_cast(h2v,v); return (float)h[0]; }
__device__ __forceinline__ float hi16(unsigned v){ h2v h=__builtin_bit_cast(h2v,v); return (float)h[1]; }
__device__ __forceinline__ float hdot2(unsigned uw, unsigned ux, float acc){
  h2v a=__builtin_bit_cast(h2v,uw), b=__builtin_bit_cast(h2v,ux);
#if __has_builtin(__builtin_amdgcn_fdot2)
  return __builtin_amdgcn_fdot2(a,b,acc,false);
#else
  return acc + (float)a[0]*(float)b[0] + (float)a[1]*(float)b[1];
#endif
}
__device__ __forceinline__ unsigned aload(const unsigned* p){
  return __hip_atomic_load(p,__ATOMIC_RELAXED,AGT);
}
__device__ __forceinline__ unsigned long long aload64(const unsigned long long* p){
  return __hip_atomic_load(p,__ATOMIC_RELAXED,AGT);
}
__device__ __forceinline__ void astore(unsigned* p, unsigned v){
  __hip_atomic_store(p,v,__ATOMIC_RELAXED,AGT);
}

// ---------------- prep kernels ----------------

__global__ __launch_bounds__(256) void k_postab(float* __restrict__ pt){
  int idx=blockIdx.x*256+threadIdx.x; if(idx>=SQ*200) return;
  int t=idx/200, j=idx%200;
  double ang=(double)(t+1)*pow(10000.0, -(double)(2*(j/2))/200.0);
  pt[idx]=(float)((j&1)? cos(ang) : sin(ang));
}

// W_e[k][j] = sum_m tgt_W[k][m] * Wih1[m][j]   (72 x 4096)
__global__ __launch_bounds__(256) void k_we(const float* __restrict__ tgtW, const float* __restrict__ Wih1, float* __restrict__ We){
  int idx=blockIdx.x*256+threadIdx.x;
  int k=idx>>12, j=idx&4095;
  float acc=0.f;
  for(int m=0;m<200;m++) acc+=tgtW[k*200+m]*Wih1[(size_t)m*4096+j];
  We[idx]=acc;
}

// bias[3][4096]
__global__ __launch_bounds__(256) void k_bias(const float* __restrict__ tgtb, const float* __restrict__ Wih1,
    const float* __restrict__ bih1,const float* __restrict__ bhh1,const float* __restrict__ bih2,const float* __restrict__ bhh2,
    const float* __restrict__ bih3,const float* __restrict__ bhh3,float* __restrict__ bias){
  int idx=blockIdx.x*256+threadIdx.x; if(idx>=3*4096) return;
  int l=idx>>12, j=idx&4095;
  float v;
  if(l==0){ v=bih1[j]+bhh1[j]; for(int m=0;m<200;m++) v+=tgtb[m]*Wih1[(size_t)m*4096+j]; }
  else if(l==1) v=bih2[j]+bhh2[j];
  else v=bih3[j]+bhh3[j];
  bias[idx]=v;
}

// packed f16 weights, unit-major [cell][u][k2][4gates] with per-unit k2 padding
// cell0: 576 k2 (K=1096 real), stride 2304 u32 ; cell1/2: 1056 k2 (K=2048), stride 4224 u32
__global__ __launch_bounds__(256) void k_packf(const float* __restrict__ We, const float* __restrict__ Whh1,
  const float* __restrict__ Wih2, const float* __restrict__ Whh2,
  const float* __restrict__ Wih3, const float* __restrict__ Whh3, unsigned* __restrict__ P){
  size_t idx=(size_t)blockIdx.x*256+threadIdx.x; // exactly 11,010,048
  const float *A, *Bm; size_t l; int stride, KA, K;
  if(idx < 2359296u){ l=idx; stride=2304; A=We; Bm=Whh1; KA=72; K=1096; }
  else if(idx < 6684672u){ l=idx-2359296u; stride=4224; A=Wih2; Bm=Whh2; KA=1024; K=2048; }
  else { l=idx-6684672u; stride=4224; A=Wih3; Bm=Whh3; KA=1024; K=2048; }
  int u=(int)(l/(size_t)stride); int r=(int)(l-(size_t)u*stride);
  int k2=r>>2, g=r&3, k=2*k2;
  float w0=0.f,w1=0.f;
  if(k<K){
    int col=g*1024+u;
    w0 = (k   < KA)? A[(size_t)k*4096+col]      : Bm[(size_t)(k-KA)*4096+col];
    w1 = (k+1 < KA)? A[(size_t)(k+1)*4096+col]  : Bm[(size_t)(k+1-KA)*4096+col];
  }
  P[idx]=pack16(w0,w1);
}

// outWT[j][u] = out_W[u][j] for u<1024 (h2 part), [72][1024]
__global__ __launch_bounds__(256) void k_outwt(const float* __restrict__ outW, float* __restrict__ outWT){
  int idx=blockIdx.x*256+threadIdx.x; if(idx>=72*1024) return;
  int j=idx>>10, u=idx&1023;
  outWT[idx]=outW[(size_t)u*72+j];
}

// ---------------- encoder ----------------

__global__ __launch_bounds__(256) void k_embed(const float* __restrict__ src, const float* __restrict__ W,
    const float* __restrict__ bias, const float* __restrict__ posb, float* __restrict__ xout){
  __shared__ float s[8][438];
  int row0=blockIdx.x*8, tid=threadIdx.x;
  for(int idx=tid; idx<8*438; idx+=256){ int r=idx/438,k=idx%438; s[r][k]=src[(size_t)(row0+r)*438+k]; }
  __syncthreads();
  int j=tid; if(j<200){
    float acc[8];
    #pragma unroll
    for(int r=0;r<8;r++){ int t=(row0+r)%SQ; acc[r]=bias[j]+posb[t*200+j]; }
    for(int k=0;k<438;k++){
      float w=W[(size_t)k*200+j];
      #pragma unroll
      for(int r=0;r<8;r++) acc[r]+=s[r][k]*w;
    }
    for(int r=0;r<8;r++) xout[(size_t)(row0+r)*200+j]=acc[r];
  }
}

template<int K,int N,int CPT,bool RELU>
__global__ __launch_bounds__(256) void k_gemm8(const float* __restrict__ A, const float* __restrict__ W,
    const float* __restrict__ bias, float* __restrict__ out){
  __shared__ float s[8][K];
  int row0=blockIdx.x*8, tid=threadIdx.x;
  for(int idx=tid; idx<8*K; idx+=256){ int r=idx/K,k=idx%K; s[r][k]=A[(size_t)(row0+r)*K+k]; }
  __syncthreads();
  int j0=tid*CPT;
  float acc[8][CPT];
  #pragma unroll
  for(int r=0;r<8;r++)
    #pragma unroll
    for(int c=0;c<CPT;c++) acc[r][c]=bias[j0+c];
  for(int k=0;k<K;k++){
    float w[CPT];
    #pragma unroll
    for(int c=0;c<CPT;c++) w[c]=W[(size_t)k*N+j0+c];
    #pragma unroll
    for(int r=0;r<8;r++){ float a=s[r][k];
      #pragma unroll
      for(int c=0;c<CPT;c++) acc[r][c]+=a*w[c];
    }
  }
  #pragma unroll
  for(int r=0;r<8;r++)
    #pragma unroll
    for(int c=0;c<CPT;c++){ float v=acc[r][c]; if(RELU) v=fmaxf(v,0.f); out[(size_t)(row0+r)*N+j0+c]=v; }
}

__global__ __launch_bounds__(256) void k_attn(const float* __restrict__ Q, const float* __restrict__ Km,
    const float* __restrict__ V, float* __restrict__ O){
  int bid=blockIdx.x;
  int it=bid%225; int h=(bid/225)&7; int b=bid/1800;
  int i0=it*8;
  int j0=i0-100; if(j0<0) j0=0;
  int j1=i0+7+101; if(j1>SQ) j1=SQ;
  int JN=j1-j0;
  __shared__ unsigned short kld[208][66];
  __shared__ unsigned short vld[208][66];
  __shared__ float q[8][64];
  __shared__ float sc[8][208];
  int tid=threadIdx.x;
  for(int idx=tid; idx<JN*64; idx+=256){
    int j=idx>>6, d=idx&63;
    size_t src=((size_t)(b*SQ+j0+j)*8+h)*64+d;
    kld[j][d]=f2bf(Km[src]);
    vld[j][d]=f2bf(V[src]);
  }
  for(int idx=tid; idx<8*64; idx+=256){ int r=idx>>6,d=idx&63; q[r][d]=Q[((size_t)(b*SQ+i0+r)*8+h)*64+d]; }
  __syncthreads();
  {
    int r=tid>>5, js=tid&31;
    int i=i0+r;
    for(int j=js;j<JN;j+=32){
      int jg=j0+j; int diff=i-jg; if(diff<0) diff=-diff;
      float s=-1e30f;
      if(diff<=100){
        s=0.f;
        for(int d=0;d<64;d++) s+=q[r][d]*bf2f(kld[j][d]);
        s*=0.125f;
      }
      sc[r][j]=s;
    }
  }
  __syncthreads();
  {
    int wv=tid>>6, lane=tid&63;
    for(int rr=wv*2; rr<wv*2+2; rr++){
      float m=-1e30f;
      for(int j=lane;j<JN;j+=64) m=fmaxf(m,sc[rr][j]);
      for(int o=32;o;o>>=1) m=fmaxf(m,__shfl_xor(m,o));
      float sum=0.f;
      for(int j=lane;j<JN;j+=64){ float e=__expf(sc[rr][j]-m); sc[rr][j]=e; sum+=e; }
      for(int o=32;o;o>>=1) sum+=__shfl_xor(sum,o);
      float inv=1.f/sum;
      for(int j=lane;j<JN;j+=64) sc[rr][j]*=inv;
    }
  }
  __syncthreads();
  {
    int d=tid&63, rb=tid>>6;
    for(int rr=rb; rr<8; rr+=4){
      float acc=0.f;
      for(int j=0;j<JN;j++) acc+=sc[rr][j]*bf2f(vld[j][d]);
      O[((size_t)(b*SQ+i0+rr)*8+h)*64+d]=acc;
    }
  }
}

template<int K>
__global__ __launch_bounds__(256) void k_matln(const float* __restrict__ A, const float* __restrict__ W,
    const float* __restrict__ bias, const float* __restrict__ g, const float* __restrict__ bt, float* __restrict__ x){
  __shared__ float s[8][K];
  __shared__ float y[8][200];
  int row0=blockIdx.x*8, tid=threadIdx.x;
  for(int idx=tid; idx<8*K; idx+=256){ int r=idx/K,k=idx%K; s[r][k]=A[(size_t)(row0+r)*K+k]; }
  __syncthreads();
  if(tid<200){
    int j=tid;
    float acc[8];
    #pragma unroll
    for(int r=0;r<8;r++) acc[r]=bias[j];
    for(int k=0;k<K;k++){
      float w=W[(size_t)k*200+j];
      #pragma unroll
      for(int r=0;r<8;r++) acc[r]+=s[r][k]*w;
    }
    #pragma unroll
    for(int r=0;r<8;r++) y[r][j]=acc[r]+x[(size_t)(row0+r)*200+j];
  }
  __syncthreads();
  int wv=tid>>6, lane=tid&63;
  for(int rr=wv*2; rr<wv*2+2; rr++){
    float sm=0.f,s2=0.f;
    for(int j=lane;j<200;j+=64){ float v=y[rr][j]; sm+=v; s2+=v*v; }
    for(int o=32;o;o>>=1){ sm+=__shfl_xor(sm,o); s2+=__shfl_xor(s2,o); }
    float mean=sm*(1.f/200.f);
    float var=s2*(1.f/200.f)-mean*mean;
    float inv=rsqrtf(var+1e-5f);
    for(int j=lane;j<200;j+=64) x[(size_t)(row0+rr)*200+j]=(y[rr][j]-mean)*inv*g[j]+bt[j];
  }
}

__global__ __launch_bounds__(320) void k_encpart(const float* __restrict__ x, const float* __restrict__ outW,
    const float* __restrict__ outb, float* __restrict__ ep){
  int t=blockIdx.x, tid=threadIdx.x;
  __shared__ float el[4][200];
  for(int idx=tid; idx<800; idx+=320){ int b=idx/200,k=idx%200; el[b][k]=x[((size_t)b*SQ+t)*200+k]; }
  __syncthreads();
  if(tid<288){
    int b=tid/72, j=tid%72;
    float acc=outb[j];
    for(int k=0;k<200;k++) acc+=el[b][k]*outW[(size_t)(1024+k)*72+j];
    ep[((size_t)b*SQ+t)*72+j]=acc;
  }
}

// ---------------- persistent decoder ----------------
// 256 blocks x 512 threads, 1 block/CU. Block b owns u in {4b..4b+3} of each
// cell, full K in-block. Weights in VGPRs. h broadcast rows [par][layer][pr][b]
// match the LDS xs2 layout -> coalesced u64 staging. Tree barrier (16x16)
// avoids same-address atomic serialization at the coherence point.

__device__ __forceinline__ void gridbar(unsigned* bar, unsigned gen){
  __syncthreads();   // drains vmcnt per wave -> h stores retired
  if(threadIdx.x==0){
    int g=blockIdx.x>>4;   // 16 groups of 16 blocks
    unsigned r=__hip_atomic_fetch_add(&bar[g*32],1u,__ATOMIC_RELAXED,AGT);
    if(r==gen*16u+15u){
      unsigned rt=__hip_atomic_fetch_add(&bar[16*32],1u,__ATOMIC_RELAXED,AGT);
      if(rt==gen*16u+15u){
        __hip_atomic_store(&bar[17*32],gen+1u,__ATOMIC_RELAXED,AGT);
      }
    }
    unsigned f;
    do{ __builtin_amdgcn_s_sleep(1);
        f=__hip_atomic_load(&bar[17*32],__ATOMIC_RELAXED,AGT);
    }while(f<gen+1u);
  }
  __syncthreads();
}

__global__ __launch_bounds__(512,2) void k_dec(
  const uint4* __restrict__ P4, const float* __restrict__ bias,
  unsigned* __restrict__ hbufU, unsigned* __restrict__ fbbufU,
  unsigned* __restrict__ h2allU, unsigned* __restrict__ bar,
  const float* __restrict__ tgt, const float* __restrict__ bos,
  const float* __restrict__ h_init, const float* __restrict__ c_init,
  const float* __restrict__ encp, const float* __restrict__ outWT)
{
  __shared__ __align__(16) unsigned xs2[2688*4]; // 43008 B, f16-pair x, [row][4 batches]
  __shared__ float red[16*513];                  // 32832 B padded partial sums
  __shared__ float gsum[192];
  __shared__ float c_lds[48];
  __shared__ float htmp[48];
  __shared__ float ldspad[1200];                 // force 1 block/CU (>80KB total)
  int tid=threadIdx.x, blk=blockIdx.x;
  if(tid==0) ldspad[0]=0.f;

  // thread -> (unit, k-split lane); wave-uniform category boundaries
  int uu, ks;
  if(tid<128){ uu=tid>>5; ks=tid&31; }
  else if(tid<320){ int l=tid-128; uu=4+l/48; ks=l-(uu-4)*48; }
  else { int l=tid-320; uu=8+l/48; ks=l-(uu-8)*48; }
  int cell = uu<4?0:(uu<8?1:2);
  int u_loc=uu&3, u_glob=blk*4+u_loc;
  size_t ubase4 = (cell==0)? (size_t)u_glob*576 :
                  (cell==1)? (589824u + (size_t)u_glob*1056) :
                             (1671168u + (size_t)u_glob*1056);
  int xoff = (cell==0)?0:(cell==1?576:1632);

  // t-invariant weight preload into VGPRs
  uint4 w[22];
  if(tid<128){
    #pragma unroll
    for(int i=0;i<18;i++) w[i]=P4[ubase4 + (size_t)ks + (size_t)i*32];
  } else {
    #pragma unroll
    for(int i=0;i<22;i++) w[i]=P4[ubase4 + (size_t)ks + (size_t)i*48];
  }

  // ---- per-thread stage descriptors (t-invariant) ----
  // row r=tid+512*q: type 0=h-row (dlp=(layer*512+pr)*2 u64 idx), 1=dec_in (dlp=j), 2=pad/none
  int dty[6], dlp[6];
  #pragma unroll
  for(int q=0;q<6;q++){
    int r=tid+512*q; dty[q]=2; dlp[q]=0;
    if(r<2688){
      int cl, rr;
      if(r<576){cl=0;rr=r;} else if(r<1632){cl=1;rr=r-576;} else {cl=2;rr=r-1632;}
      if(cl==0){
        if(rr<36){ dty[q]=1; dlp[q]=2*rr; }
        else if(rr<548){ dty[q]=0; dlp[q]=(0*512+(rr-36))*2; }
      } else {
        int l0=(cl==1)?0:1;
        if(rr<512){ dty[q]=0; dlp[q]=(l0*512+rr)*2; }
        else if(rr<1024){ dty[q]=0; dlp[q]=((l0+1)*512+(rr-512))*2; }
      }
    }
  }

  // c state init (lives in LDS for all 1800 steps)
  if(tid<48){
    int uu0=tid>>2, b0=tid&3;
    int cl=uu0<4?0:(uu0<8?1:2);
    c_lds[tid]=c_init[((size_t)cl*4+b0)*1024 + (size_t)blk*4+(uu0&3)];
  }
  __syncthreads();

  const unsigned long long* hb64=(const unsigned long long*)hbufU;
  unsigned gen=0;
  for(int t=0;t<SQ;t++){
    bool fb=(t>0)&&(t%11==0);
    if(fb){
      // blocks 0..71: dec_in(t) = h2(t-1) @ outW_h + encp(t-1)
      if(blk<72 && tid<256){
        int j=blk, b=tid>>6, lane=tid&63, pv=(t-1)&1;
        float s=0.f;
        #pragma unroll
        for(int q=0;q<8;q++){
          int u2=lane+q*64;
          unsigned v=aload(&hbufU[(size_t)(((pv*3+2)*512)+u2)*4+b]);
          s += lo16(v)*outWT[(size_t)j*1024+2*u2] + hi16(v)*outWT[(size_t)j*1024+2*u2+1];
        }
        #pragma unroll
        for(int o=32;o;o>>=1) s+=__shfl_xor(s,o);
        if(lane==0) astore(&fbbufU[b*72+j], __float_as_uint(s + encp[((size_t)b*SQ+(t-1))*72+j]));
      }
      gridbar(bar,gen); gen++;
    }

    // ---- stage x (f16 pairs) ----
    if(t==0){
      // initial staging from bos/h_init; also zeroes pad rows (persist thereafter)
      #pragma unroll
      for(int q=0;q<6;q++){
        if(q==5 && tid>=128) break;
        uint4 vv={0u,0u,0u,0u};
        if(dty[q]==1){
          int j=dlp[q];
          const float2 f0=*(const float2*)&bos[0*72+j];
          const float2 f1=*(const float2*)&bos[1*72+j];
          const float2 f2=*(const float2*)&bos[2*72+j];
          const float2 f3=*(const float2*)&bos[3*72+j];
          vv.x=pack16(f0.x,f0.y); vv.y=pack16(f1.x,f1.y);
          vv.z=pack16(f2.x,f2.y); vv.w=pack16(f3.x,f3.y);
        } else if(dty[q]==0){
          int lp=dlp[q]>>10, pr=(dlp[q]>>1)&511;
          const float2 f0=*(const float2*)&h_init[((size_t)lp*4+0)*1024+2*pr];
          const float2 f1=*(const float2*)&h_init[((size_t)lp*4+1)*1024+2*pr];
          const float2 f2=*(const float2*)&h_init[((size_t)lp*4+2)*1024+2*pr];
          const float2 f3=*(const float2*)&h_init[((size_t)lp*4+3)*1024+2*pr];
          vv.x=pack16(f0.x,f0.y); vv.y=pack16(f1.x,f1.y);
          vv.z=pack16(f2.x,f2.y); vv.w=pack16(f3.x,f3.y);
        }
        *(uint4*)&xs2[(size_t)(tid+512*q)*4]=vv;
      }
    } else {
      size_t pvoff=(size_t)(((t-1)&1)*3*512*2);
      #pragma unroll
      for(int q=0;q<6;q++){
        if(q==5 && tid>=128) break;
        int ty=dty[q];
        if(ty==0){
          unsigned long long a=aload64(hb64+pvoff+dlp[q]);
          unsigned long long c=aload64(hb64+pvoff+dlp[q]+1);
          uint4 vv; vv.x=(unsigned)a; vv.y=(unsigned)(a>>32);
          vv.z=(unsigned)c; vv.w=(unsigned)(c>>32);
          *(uint4*)&xs2[(size_t)(tid+512*q)*4]=vv;
        } else if(ty==1){
          int j=dlp[q];
          uint4 vv;
          if(fb){
            vv.x=pack16(__uint_as_float(aload(&fbbufU[0*72+j])),__uint_as_float(aload(&fbbufU[0*72+j+1])));
            vv.y=pack16(__uint_as_float(aload(&fbbufU[1*72+j])),__uint_as_float(aload(&fbbufU[1*72+j+1])));
            vv.z=pack16(__uint_as_float(aload(&fbbufU[2*72+j])),__uint_as_float(aload(&fbbufU[2*72+j+1])));
            vv.w=pack16(__uint_as_float(aload(&fbbufU[3*72+j])),__uint_as_float(aload(&fbbufU[3*72+j+1])));
          } else {
            const float2 f0=*(const float2*)&tgt[((size_t)0*SQ+t)*72+j];
            const float2 f1=*(const float2*)&tgt[((size_t)1*SQ+t)*72+j];
            const float2 f2=*(const float2*)&tgt[((size_t)2*SQ+t)*72+j];
            const float2 f3=*(const float2*)&tgt[((size_t)3*SQ+t)*72+j];
            vv.x=pack16(f0.x,f0.y); vv.y=pack16(f1.x,f1.y);
            vv.z=pack16(f2.x,f2.y); vv.w=pack16(f3.x,f3.y);
          }
          *(uint4*)&xs2[(size_t)(tid+512*q)*4]=vv;
        }
      }
    }
    __syncthreads();

    // ---- gates: acc[g*4+b] over this thread's k slice ----
    {
      float acc[16];
      #pragma unroll
      for(int a=0;a<16;a++) acc[a]=0.f;
      auto run=[&](int NIT,int NKS){
        #pragma unroll
        for(int i=0;i<22;i++){
          if(i>=NIT) break;
          const uint4 xv=*(const uint4*)&xs2[(size_t)(xoff+ks+i*NKS)*4];
          const unsigned* wu=(const unsigned*)&w[i];
          const unsigned* xu=(const unsigned*)&xv;
          #pragma unroll
          for(int g=0;g<4;g++)
            #pragma unroll
            for(int b=0;b<4;b++)
              acc[g*4+b]=hdot2(wu[g],xu[b],acc[g*4+b]);
        }
      };
      if(tid<128) run(18,32); else run(22,48);
      #pragma unroll
      for(int a=0;a<16;a++) red[a*513+tid]=acc[a];
    }
    __syncthreads();

    // ---- per-unit reduce + bias ----
    if(tid<192){
      int uuo=tid>>4, a=tid&15;
      int base,n;
      if(uuo<4){base=uuo*32;n=32;} else {base=128+(uuo-4)*48;n=48;}
      float s=0.f;
      for(int j2=0;j2<n;j2++) s+=red[a*513+base+j2];
      int cl=uuo<4?0:(uuo<8?1:2), g=a>>2;
      gsum[tid]=s+bias[(size_t)cl*4096+(size_t)g*1024+blk*4+(uuo&3)];
    }
    __syncthreads();

    // ---- pointwise LSTM ----
    if(tid<48){
      int uup=tid>>2,b=tid&3;
      float gi=gsum[uup*16+b],gf=gsum[uup*16+4+b],gg=gsum[uup*16+8+b],go=gsum[uup*16+12+b];
      float cp=c_lds[tid];
      float cn=sigm(gf)*cp+sigm(gi)*tanhf(gg);
      float hn=sigm(go)*tanhf(cn);
      c_lds[tid]=cn; htmp[tid]=hn;
    }
    __syncthreads();
    if(tid<48 && !(tid&4)){ // even unit: pack (u, u+1) pair
      int uup=tid>>2,b=tid&3;
      int cl=uup<4?0:(uup<8?1:2), ul=uup&3;
      unsigned v=pack16(htmp[tid],htmp[tid+4]);
      int pr=blk*2+(ul>>1);
      astore(&hbufU[(size_t)(((t&1)*3+cl)*512+pr)*4+b], v);
      if(cl==2) astore(&h2allU[((size_t)t*4+b)*512+pr], v);
    }
    gridbar(bar,gen); gen++;
  }
}

// final: out[b][t][j] = h2(t) @ out_W[:1024] + enc_part[b][t][j]
__global__ __launch_bounds__(320) void k_out(const unsigned* __restrict__ h2allU, const float* __restrict__ outW,
    const float* __restrict__ enc_part, float* __restrict__ out){
  int t=blockIdx.x, tid=threadIdx.x;
  __shared__ float h2l[4][1024];
  for(int idx=tid; idx<2048; idx+=320){
    int b=idx>>9, p=idx&511;
    unsigned v=h2allU[((size_t)t*4+b)*512+p];
    h2l[b][2*p]=lo16(v); h2l[b][2*p+1]=hi16(v);
  }
  __syncthreads();
  if(tid<288){
    int b=tid/72, j=tid%72;
    float acc=enc_part[((size_t)b*SQ+t)*72+j];
    for(int u=0;u<1024;u++) acc+=h2l[b][u]*outW[(size_t)u*72+j];
    out[((size_t)b*SQ+t)*72+j]=acc;
  }
}

// ---------------- host ----------------
extern "C" void kernel_launch(void* const* d_in, const int* in_sizes, int n_in,
                              void* d_out, int out_size, void* d_ws, size_t ws_size,
                              hipStream_t stream) {
  (void)in_sizes; (void)n_in; (void)out_size; (void)ws_size;
  const float* src   =(const float*)d_in[0];
  const float* tgt   =(const float*)d_in[1];
  const float* bos   =(const float*)d_in[2];
  const float* h_init=(const float*)d_in[3];
  const float* c_init=(const float*)d_in[4];
  const float* eW    =(const float*)d_in[6];
  const float* eb    =(const float*)d_in[7];
  const float* Wq    =(const float*)d_in[8];
  const float* bq    =(const float*)d_in[9];
  const float* Wk    =(const float*)d_in[10];
  const float* bk    =(const float*)d_in[11];
  const float* Wv    =(const float*)d_in[12];
  const float* bv    =(const float*)d_in[13];
  const float* Wo    =(const float*)d_in[14];
  const float* bo    =(const float*)d_in[15];
  const float* ln1g  =(const float*)d_in[16];
  const float* ln1b  =(const float*)d_in[17];
  const float* W1    =(const float*)d_in[18];
  const float* b1    =(const float*)d_in[19];
  const float* W2    =(const float*)d_in[20];
  const float* b2    =(const float*)d_in[21];
  const float* ln2g  =(const float*)d_in[22];
  const float* ln2b  =(const float*)d_in[23];
  const float* tgtW  =(const float*)d_in[24];
  const float* tgtb  =(const float*)d_in[25];
  const float* Wih1  =(const float*)d_in[26];
  const float* Whh1  =(const float*)d_in[27];
  const float* bih1  =(const float*)d_in[28];
  const float* bhh1  =(const float*)d_in[29];
  const float* Wih2  =(const float*)d_in[30];
  const float* Whh2  =(const float*)d_in[31];
  const float* bih2  =(const float*)d_in[32];
  const float* bhh2  =(const float*)d_in[33];
  const float* Wih3  =(const float*)d_in[34];
  const float* Whh3  =(const float*)d_in[35];
  const float* bih3  =(const float*)d_in[36];
  const float* bhh3  =(const float*)d_in[37];
  const float* outW  =(const float*)d_in[38];
  const float* outb  =(const float*)d_in[39];
  float* out=(float*)d_out;

  char* wsb=(char*)d_ws; size_t off=0;
  auto alloc=[&](size_t bytes)->void*{ void* p=wsb+off; off+=(bytes+255)&~(size_t)255; return p; };
  unsigned* Pf   =(unsigned*)alloc((size_t)11010048*4);   // 44.04 MB packed f16 weights
  float* We   =(float*)alloc((size_t)72*4096*4);
  float* bias =(float*)alloc((size_t)3*4096*4);
  float* outWT=(float*)alloc((size_t)72*1024*4);
  unsigned* hbufU =(unsigned*)alloc((size_t)2*3*512*4*4);
  unsigned* fbbufU=(unsigned*)alloc((size_t)4*72*4);
  unsigned* bar   =(unsigned*)alloc(4096);
  float* encp =(float*)alloc((size_t)7200*72*4);
  float* posb =(float*)alloc((size_t)SQ*200*4);
  float* xb   =(float*)alloc((size_t)7200*200*4);
  float* qb   =(float*)alloc((size_t)7200*512*4);
  float* kb   =(float*)alloc((size_t)7200*512*4);
  float* vb   =(float*)alloc((size_t)7200*512*4);
  float* ob   =(float*)alloc((size_t)7200*512*4);
  unsigned* h2allU=(unsigned*)qb; // alias: dead after encoder; 14.74MB fits
  float* mid  =vb;                // alias for FFN intermediate
  (void)kb; (void)ob;

  // prep
  k_postab<<<(SQ*200+255)/256,256,0,stream>>>(posb);
  k_we<<<72*4096/256,256,0,stream>>>(tgtW,Wih1,We);
  k_bias<<<48,256,0,stream>>>(tgtb,Wih1,bih1,bhh1,bih2,bhh2,bih3,bhh3,bias);
  k_packf<<<43008,256,0,stream>>>(We,Whh1,Wih2,Whh2,Wih3,Whh3,Pf);
  k_outwt<<<(72*1024+255)/256,256,0,stream>>>(outW,outWT);

  // encoder
  k_embed<<<900,256,0,stream>>>(src,eW,eb,posb,xb);
  for(int l=0;l<2;l++){
    k_gemm8<200,512,2,false><<<900,256,0,stream>>>(xb,Wq+(size_t)l*200*512,bq+l*512,qb);
    k_gemm8<200,512,2,false><<<900,256,0,stream>>>(xb,Wk+(size_t)l*200*512,bk+l*512,kb);
    k_gemm8<200,512,2,false><<<900,256,0,stream>>>(xb,Wv+(size_t)l*200*512,bv+l*512,vb);
    k_attn<<<7200,256,0,stream>>>(qb,kb,vb,ob);
    k_matln<512><<<900,256,0,stream>>>(ob,Wo+(size_t)l*512*200,bo+l*200,ln1g+l*200,ln1b+l*200,xb);
    k_gemm8<200,1024,4,true><<<900,256,0,stream>>>(xb,W1+(size_t)l*200*1024,b1+l*1024,mid);
    k_matln<1024><<<900,256,0,stream>>>(mid,W2+(size_t)l*1024*200,b2+l*200,ln2g+l*200,ln2b+l*200,xb);
  }
  k_encpart<<<SQ,320,0,stream>>>(xb,outW,outb,encp);

  // persistent decoder (single dispatch, tree grid barrier per step)
  hipMemsetAsync(bar,0,4096,stream);
  k_dec<<<NBLK,512,0,stream>>>((const uint4*)Pf,bias,hbufU,fbbufU,h2allU,bar,
                               tgt,bos,h_init,c_init,encp,outWT);

  // output projection
  k_out<<<SQ,320,0,stream>>>(h2allU,outW,encp,out);
}